// Round 8
// baseline (122.628 us; speedup 1.0000x reference)
//
#include <hip/hip_runtime.h>

#define NB 8
#define NO 2048
#define NQ 2048
#define ND 128
#define R  12        // Taylor terms for exp(x), x = tq*to/sigma^2 in [0,1] -> err ~ 6e-9

// Single kernel, per-batch producer/consumer handoff via device-scope atomics.
// grid 256 = 8 b x 32 sub; block 512; all blocks co-resident (<= 2 blocks/CU needed).
// P1: moments for o-chunk `sub` -> Mpart[b][sub][12][128], spart[b][sub][12]
// block sub==0 of each batch: reduce + W-fold -> Pg[b], sg[b]; others wait on done flag.
// P3: every block emits q-tile `sub` (64 q rows).
__global__ __launch_bounds__(512, 1) void fused_kernel(
    const float* __restrict__ obs_emb, const float* __restrict__ obs_times,
    const float* __restrict__ query_times, const float* __restrict__ obs_mask,
    const float* __restrict__ log_sigma, const float* __restrict__ W_proj,
    const float* __restrict__ b_proj, float* __restrict__ Mpart,
    float* __restrict__ spart, float* __restrict__ Pg, float* __restrict__ sg,
    int* cnt, float* __restrict__ out)
{
  __shared__ __align__(16) float smem[6144];  // 24 KB: P1 Lacc[4][12][128]; P2 Ml[1536]+Pl@2048[8*196]
  __shared__ float Ls[4][R];
  __shared__ float slb[R];

  const int tid = threadIdx.x;
  const int b   = blockIdx.x & 7;             // XCD-aligned batch
  const int sub = blockIdx.x >> 3;            // 0..31: o-chunk (P1) / q-tile (P3)

  const float ls     = log_sigma[0];
  const float inv_s2 = __expf(-2.0f * ls);    // 1/sigma^2
  const float kp     = 0.5f * inv_s2;

  // ---------------- phase 1: moment chunk ----------------
  {
    const int d    = tid & 127;
    const int osub = tid >> 7;                // 0..3, 16 o's each
    const int o0   = sub * 64 + osub * 16;

    float ev[16], tof[16], mkf[16];
    #pragma unroll
    for (int i = 0; i < 16; ++i) {
      tof[i] = obs_times[b * NO + o0 + i];
      mkf[i] = obs_mask[b * NO + o0 + i];
      ev[i]  = obs_emb[((size_t)(b * NO + o0 + i)) * ND + d];
    }
    const float inv_np1[R] = {1.f, 0.5f, 1.f/3.f, 0.25f, 0.2f, 1.f/6.f,
                              1.f/7.f, 0.125f, 1.f/9.f, 0.1f, 1.f/11.f, 1.f/12.f};
    float acc[R], sl[R];
    #pragma unroll
    for (int n = 0; n < R; ++n) { acc[n] = 0.f; sl[n] = 0.f; }
    #pragma unroll
    for (int i = 0; i < 16; ++i) {
      const float u = tof[i] * inv_s2;
      float c = mkf[i] * __expf(-kp * tof[i] * tof[i]);
      #pragma unroll
      for (int n = 0; n < R; ++n) {
        acc[n] = fmaf(c, ev[i], acc[n]);
        sl[n] += c;
        c *= u * inv_np1[n];
      }
    }
    #pragma unroll
    for (int n = 0; n < R; ++n) smem[(osub * R + n) * ND + d] = acc[n];
    if (d == 0) {
      #pragma unroll
      for (int n = 0; n < R; ++n) Ls[osub][n] = sl[n];
    }
    __syncthreads();
    float* Mout = Mpart + ((size_t)(b * 32 + sub)) * (R * ND);
    #pragma unroll
    for (int k = 0; k < 3; ++k) {
      const int e = k * 512 + tid;            // flat n*128+d
      Mout[e] = (smem[e] + smem[1536 + e]) + (smem[3072 + e] + smem[4608 + e]);
    }
    if (tid < R)
      spart[(b * 32 + sub) * R + tid] =
          (Ls[0][tid] + Ls[1][tid]) + (Ls[2][tid] + Ls[3][tid]);
  }

  __threadfence();                            // device-scope release of Mpart/spart
  __syncthreads();
  if (tid == 0)
    __hip_atomic_fetch_add(&cnt[b], 1, __ATOMIC_RELEASE, __HIP_MEMORY_SCOPE_AGENT);

  if (sub == 0) {
    // ---------------- phase 2 (one block per batch): reduce + W fold ----------------
    if (tid == 0) {
      while (__hip_atomic_load(&cnt[b], __ATOMIC_ACQUIRE, __HIP_MEMORY_SCOPE_AGENT) < 32)
        __builtin_amdgcn_s_sleep(2);
    }
    __syncthreads();                          // all chunks visible; smem (Lacc) free

    const float* Mp = Mpart + (size_t)b * 32 * (R * ND);
    float vout[3];
    #pragma unroll
    for (int k = 0; k < 3; ++k) {
      const int e = k * 512 + tid;
      float v0 = 0.f, v1 = 0.f, v2 = 0.f, v3 = 0.f;
      #pragma unroll
      for (int ch = 0; ch < 32; ch += 4) {
        v0 += Mp[(ch + 0) * (R * ND) + e];
        v1 += Mp[(ch + 1) * (R * ND) + e];
        v2 += Mp[(ch + 2) * (R * ND) + e];
        v3 += Mp[(ch + 3) * (R * ND) + e];
      }
      vout[k] = (v0 + v1) + (v2 + v3);
    }
    float sv = 0.f;
    if (tid < R) {
      const float* sp = spart + b * 32 * R;
      #pragma unroll
      for (int ch = 0; ch < 32; ++ch) sv += sp[ch * R + tid];
    }
    #pragma unroll
    for (int k = 0; k < 3; ++k) smem[k * 512 + tid] = vout[k];  // Ml
    if (tid < R) { slb[tid] = sv; sg[b * R + tid] = sv; }
    __syncthreads();

    // P = M @ W^T  (thread: e = tid>>2, 3 n's at nh=(tid&3)*3)
    const int e  = tid >> 2;
    const int nh = (tid & 3) * 3;
    const float4* Wr = reinterpret_cast<const float4*>(W_proj) + e * 32;
    const float4* M4 = reinterpret_cast<const float4*>(smem);
    float p0 = 0.f, p1 = 0.f, p2 = 0.f;
    #pragma unroll 8
    for (int d4 = 0; d4 < 32; ++d4) {
      const float4 w  = Wr[d4];
      const float4 m0 = M4[(nh + 0) * 32 + d4];
      const float4 m1 = M4[(nh + 1) * 32 + d4];
      const float4 m2 = M4[(nh + 2) * 32 + d4];
      p0 = fmaf(w.x, m0.x, fmaf(w.y, m0.y, fmaf(w.z, m0.z, fmaf(w.w, m0.w, p0))));
      p1 = fmaf(w.x, m1.x, fmaf(w.y, m1.y, fmaf(w.z, m1.z, fmaf(w.w, m1.w, p1))));
      p2 = fmaf(w.x, m2.x, fmaf(w.y, m2.y, fmaf(w.z, m2.z, fmaf(w.w, m2.w, p2))));
    }
    float* Pl = smem + 2048;                  // [eh][n][16], stride 196
    float* Pb = Pg + (size_t)b * (R * ND);
    Pl[(e >> 4) * 196 + (nh + 0) * 16 + (e & 15)] = p0;
    Pl[(e >> 4) * 196 + (nh + 1) * 16 + (e & 15)] = p1;
    Pl[(e >> 4) * 196 + (nh + 2) * 16 + (e & 15)] = p2;
    Pb[(nh + 0) * ND + e] = p0;
    Pb[(nh + 1) * ND + e] = p1;
    Pb[(nh + 2) * ND + e] = p2;
    __threadfence();                          // release Pg/sg
    __syncthreads();                          // Pl/slb ready for P3
    if (tid == 0)
      __hip_atomic_store(&cnt[NB + b], 1, __ATOMIC_RELEASE, __HIP_MEMORY_SCOPE_AGENT);
  } else {
    // ---------------- consumers: wait for fold, stage P into LDS ----------------
    if (tid == 0) {
      while (__hip_atomic_load(&cnt[NB + b], __ATOMIC_ACQUIRE, __HIP_MEMORY_SCOPE_AGENT) == 0)
        __builtin_amdgcn_s_sleep(2);
    }
    __syncthreads();                          // Pg visible; smem (Lacc) free
    const float* Pb = Pg + (size_t)b * (R * ND);
    float* Pl = smem + 2048;
    #pragma unroll
    for (int k = 0; k < 3; ++k) {
      const int w = k * 512 + tid;            // flat n*128+e
      const int n = w >> 7, e = w & 127;
      Pl[(e >> 4) * 196 + n * 16 + (e & 15)] = Pb[w];
    }
    if (tid < R) slb[tid] = sg[b * R + tid];
    __syncthreads();
  }

  // ---------------- phase 3: emit q-tile ----------------
  {
    const float* Pl = smem + 2048;
    const int q  = sub * 64 + (tid >> 3);
    const int eh = tid & 7;                   // e-range [eh*16, +16)
    const float tq = query_times[b * NQ + q];

    float c[R];
    c[0] = 1.f;
    #pragma unroll
    for (int n = 1; n < R; ++n) c[n] = c[n - 1] * tq;
    float wsum = 0.f;
    #pragma unroll
    for (int n = 0; n < R; ++n) wsum = fmaf(c[n], slb[n], wsum);
    const float inv = 1.0f / fmaxf(wsum, 1e-8f);

    const float* Pe = Pl + eh * 196;
    float4 a0 = {0,0,0,0}, a1 = {0,0,0,0}, a2 = {0,0,0,0}, a3 = {0,0,0,0};
    #pragma unroll
    for (int n = 0; n < R; ++n) {
      const float cn = c[n];
      const float4 p0 = *reinterpret_cast<const float4*>(Pe + n * 16 + 0);
      const float4 p1 = *reinterpret_cast<const float4*>(Pe + n * 16 + 4);
      const float4 p2 = *reinterpret_cast<const float4*>(Pe + n * 16 + 8);
      const float4 p3 = *reinterpret_cast<const float4*>(Pe + n * 16 + 12);
      a0.x = fmaf(cn, p0.x, a0.x); a0.y = fmaf(cn, p0.y, a0.y);
      a0.z = fmaf(cn, p0.z, a0.z); a0.w = fmaf(cn, p0.w, a0.w);
      a1.x = fmaf(cn, p1.x, a1.x); a1.y = fmaf(cn, p1.y, a1.y);
      a1.z = fmaf(cn, p1.z, a1.z); a1.w = fmaf(cn, p1.w, a1.w);
      a2.x = fmaf(cn, p2.x, a2.x); a2.y = fmaf(cn, p2.y, a2.y);
      a2.z = fmaf(cn, p2.z, a2.z); a2.w = fmaf(cn, p2.w, a2.w);
      a3.x = fmaf(cn, p3.x, a3.x); a3.y = fmaf(cn, p3.y, a3.y);
      a3.z = fmaf(cn, p3.z, a3.z); a3.w = fmaf(cn, p3.w, a3.w);
    }
    const float4* B4 = reinterpret_cast<const float4*>(b_proj) + eh * 4;
    const float4 bb0 = B4[0], bb1 = B4[1], bb2 = B4[2], bb3 = B4[3];
    float4* orow = reinterpret_cast<float4*>(out + ((size_t)(b * NQ + q)) * ND + eh * 16);
    orow[0] = make_float4(fmaf(a0.x, inv, bb0.x), fmaf(a0.y, inv, bb0.y),
                          fmaf(a0.z, inv, bb0.z), fmaf(a0.w, inv, bb0.w));
    orow[1] = make_float4(fmaf(a1.x, inv, bb1.x), fmaf(a1.y, inv, bb1.y),
                          fmaf(a1.z, inv, bb1.z), fmaf(a1.w, inv, bb1.w));
    orow[2] = make_float4(fmaf(a2.x, inv, bb2.x), fmaf(a2.y, inv, bb2.y),
                          fmaf(a2.z, inv, bb2.z), fmaf(a2.w, inv, bb2.w));
    orow[3] = make_float4(fmaf(a3.x, inv, bb3.x), fmaf(a3.y, inv, bb3.y),
                          fmaf(a3.z, inv, bb3.z), fmaf(a3.w, inv, bb3.w));
  }
}

extern "C" void kernel_launch(void* const* d_in, const int* in_sizes, int n_in,
                              void* d_out, int out_size, void* d_ws, size_t ws_size,
                              hipStream_t stream) {
  const float* obs_emb     = (const float*)d_in[0];
  const float* obs_times   = (const float*)d_in[1];
  const float* query_times = (const float*)d_in[2];
  const float* obs_mask    = (const float*)d_in[3];
  const float* log_sigma   = (const float*)d_in[4];
  const float* W_proj      = (const float*)d_in[5];
  const float* b_proj      = (const float*)d_in[6];
  float* out = (float*)d_out;

  float* Mpart = (float*)d_ws;                          // 8*32*12*128 f32 = 1.57 MB
  float* spart = Mpart + (size_t)NB * 32 * R * ND;      // 8*32*12
  float* Pg    = spart + NB * 32 * R;                   // 8*12*128
  float* sg    = Pg + NB * R * ND;                      // 8*12
  int*   cnt   = (int*)(sg + NB * R);                   // 16 ints (cnt[8] + done[8])

  hipMemsetAsync(cnt, 0, 16 * sizeof(int), stream);     // graph-legal reset each call
  fused_kernel<<<NB * 32, 512, 0, stream>>>(obs_emb, obs_times, query_times,
                                            obs_mask, log_sigma, W_proj, b_proj,
                                            Mpart, spart, Pg, sg, cnt, out);
}

// Round 9
// 48.318 us; speedup vs baseline: 2.5379x; 2.5379x over previous
//
#include <hip/hip_runtime.h>

#define NB 8
#define NO 2048
#define NQ 2048
#define ND 128
#define R  12        // Taylor terms for exp(x), x = tq*to/sigma^2 in [0,1] -> err ~ 6e-9
#define NCH 16       // o-chunks of 128 per batch

// ---------------- kernel 1: partial moment accumulation ----------------
// grid 128 = 16 ch x 8 b (b = blk&7, XCD-aligned with K2's consumers).
// Mpart[b][ch][n][d] = sum_{o in chunk} coef[o][n] * obs_emb[b][o][d]
// spart[b][ch][n]    = sum_{o in chunk} coef[o][n]
// coef[o][n] = mask_o * exp(-k*to^2) * (to/sigma^2)^n / n!
__global__ __launch_bounds__(512) void moment_kernel(
    const float* __restrict__ obs_emb, const float* __restrict__ obs_times,
    const float* __restrict__ obs_mask, const float* __restrict__ log_sigma,
    float* __restrict__ Mpart, float* __restrict__ spart)
{
  __shared__ float Lacc[4 * R * ND];   // 24 KB
  __shared__ float Ls[4][R];
  const int tid  = threadIdx.x;
  const int d    = tid & 127;
  const int osub = tid >> 7;           // 0..3, 32 o's each
  const int b    = blockIdx.x & 7;
  const int ch   = blockIdx.x >> 3;
  const int o0   = ch * 128 + osub * 32;

  const float ls     = log_sigma[0];
  const float inv_s2 = __expf(-2.0f * ls);   // 1/sigma^2
  const float kp     = 0.5f * inv_s2;

  const float inv_np1[R] = {1.f, 0.5f, 1.f/3.f, 0.25f, 0.2f, 1.f/6.f,
                            1.f/7.f, 0.125f, 1.f/9.f, 0.1f, 1.f/11.f, 1.f/12.f};
  float acc[R], sl[R];
  #pragma unroll
  for (int n = 0; n < R; ++n) { acc[n] = 0.f; sl[n] = 0.f; }

  #pragma unroll
  for (int half = 0; half < 2; ++half) {
    const int oh = o0 + half * 16;
    float ev[16], tof[16], mkf[16];
    #pragma unroll
    for (int i = 0; i < 16; ++i) {
      tof[i] = obs_times[b * NO + oh + i];    // wave-uniform
      mkf[i] = obs_mask[b * NO + oh + i];
      ev[i]  = obs_emb[((size_t)(b * NO + oh + i)) * ND + d];
    }
    #pragma unroll
    for (int i = 0; i < 16; ++i) {
      const float u = tof[i] * inv_s2;
      float c = mkf[i] * __expf(-kp * tof[i] * tof[i]);
      #pragma unroll
      for (int n = 0; n < R; ++n) {
        acc[n] = fmaf(c, ev[i], acc[n]);
        sl[n] += c;
        c *= u * inv_np1[n];
      }
    }
  }

  #pragma unroll
  for (int n = 0; n < R; ++n) Lacc[(osub * R + n) * ND + d] = acc[n];
  if (d == 0) {
    #pragma unroll
    for (int n = 0; n < R; ++n) Ls[osub][n] = sl[n];
  }
  __syncthreads();

  float* Mout = Mpart + ((size_t)(b * NCH + ch)) * (R * ND);
  #pragma unroll
  for (int k = 0; k < 3; ++k) {
    const int e = k * 512 + tid;       // flat n*ND+d
    Mout[e] = (Lacc[e] + Lacc[1536 + e]) + (Lacc[3072 + e] + Lacc[4608 + e]);
  }
  if (tid < R)
    spart[(b * NCH + ch) * R + tid] =
        (Ls[0][tid] + Ls[1][tid]) + (Ls[2][tid] + Ls[3][tid]);
}

// ---------------- kernel 2: reduce + fold W + emit ----------------
// grid 256 = 8 b x 32 q-tiles(64 q); 512 threads.
// A: M[n][d] = sum_ch Mpart (98 KB, local-XCD L2); s[n] likewise.
// B: P[n][e] = sum_d M[n][d] * W[e][d]   (LDS, layout [eh][n][16] stride 196)
// C: out[q][e] = (sum_n tq^n P[n][e]) / max(sum_n tq^n s[n], 1e-8) + b[e]
__global__ __launch_bounds__(512) void out_kernel(
    const float* __restrict__ query_times, const float* __restrict__ W_proj,
    const float* __restrict__ b_proj, const float* __restrict__ Mpart,
    const float* __restrict__ spart, float* __restrict__ out)
{
  __shared__ float Ml[R * ND];        // 6 KB
  __shared__ float Pl[8 * 196];       // 6.3 KB
  __shared__ float slb[R];
  const int tid = threadIdx.x;
  const int b   = blockIdx.x & 7;
  const int q0  = (blockIdx.x >> 3) * 64;

  // phase A: chunk reduction (fixed order -> deterministic)
  {
    const float* Mp = Mpart + (size_t)b * NCH * (R * ND);
    #pragma unroll
    for (int k = 0; k < 3; ++k) {
      const int e = k * 512 + tid;
      float v0 = 0.f, v1 = 0.f, v2 = 0.f, v3 = 0.f;
      #pragma unroll
      for (int chh = 0; chh < NCH; chh += 4) {
        v0 += Mp[(chh + 0) * (R * ND) + e];
        v1 += Mp[(chh + 1) * (R * ND) + e];
        v2 += Mp[(chh + 2) * (R * ND) + e];
        v3 += Mp[(chh + 3) * (R * ND) + e];
      }
      Ml[e] = (v0 + v1) + (v2 + v3);
    }
    if (tid < R) {
      const float* sp = spart + b * NCH * R;
      float v = 0.f;
      #pragma unroll
      for (int chh = 0; chh < NCH; ++chh) v += sp[chh * R + tid];
      slb[tid] = v;
    }
  }
  __syncthreads();

  // phase B: P = M @ W^T  (thread: e = tid>>2, 3 n's at nh=(tid&3)*3)
  {
    const int e  = tid >> 2;
    const int nh = (tid & 3) * 3;
    const float4* Wr = reinterpret_cast<const float4*>(W_proj) + e * 32;
    const float4* M4 = reinterpret_cast<const float4*>(Ml);
    float p0 = 0.f, p1 = 0.f, p2 = 0.f;
    #pragma unroll 8
    for (int d4 = 0; d4 < 32; ++d4) {
      const float4 w  = Wr[d4];
      const float4 m0 = M4[(nh + 0) * 32 + d4];
      const float4 m1 = M4[(nh + 1) * 32 + d4];
      const float4 m2 = M4[(nh + 2) * 32 + d4];
      p0 = fmaf(w.x, m0.x, fmaf(w.y, m0.y, fmaf(w.z, m0.z, fmaf(w.w, m0.w, p0))));
      p1 = fmaf(w.x, m1.x, fmaf(w.y, m1.y, fmaf(w.z, m1.z, fmaf(w.w, m1.w, p1))));
      p2 = fmaf(w.x, m2.x, fmaf(w.y, m2.y, fmaf(w.z, m2.z, fmaf(w.w, m2.w, p2))));
    }
    Pl[(e >> 4) * 196 + (nh + 0) * 16 + (e & 15)] = p0;
    Pl[(e >> 4) * 196 + (nh + 1) * 16 + (e & 15)] = p1;
    Pl[(e >> 4) * 196 + (nh + 2) * 16 + (e & 15)] = p2;
  }
  __syncthreads();

  // phase C: emit (thread: q = q0 + tid>>3, e-range [eh*16, +16))
  {
    const int q  = q0 + (tid >> 3);
    const int eh = tid & 7;
    const float tq = query_times[b * NQ + q];

    float c[R];
    c[0] = 1.f;
    #pragma unroll
    for (int n = 1; n < R; ++n) c[n] = c[n - 1] * tq;
    float wsum = 0.f;
    #pragma unroll
    for (int n = 0; n < R; ++n) wsum = fmaf(c[n], slb[n], wsum);
    const float inv = 1.0f / fmaxf(wsum, 1e-8f);

    const float* Pe = Pl + eh * 196;
    float4 a0 = {0,0,0,0}, a1 = {0,0,0,0}, a2 = {0,0,0,0}, a3 = {0,0,0,0};
    #pragma unroll
    for (int n = 0; n < R; ++n) {
      const float cn = c[n];
      const float4 p0 = *reinterpret_cast<const float4*>(Pe + n * 16 + 0);
      const float4 p1 = *reinterpret_cast<const float4*>(Pe + n * 16 + 4);
      const float4 p2 = *reinterpret_cast<const float4*>(Pe + n * 16 + 8);
      const float4 p3 = *reinterpret_cast<const float4*>(Pe + n * 16 + 12);
      a0.x = fmaf(cn, p0.x, a0.x); a0.y = fmaf(cn, p0.y, a0.y);
      a0.z = fmaf(cn, p0.z, a0.z); a0.w = fmaf(cn, p0.w, a0.w);
      a1.x = fmaf(cn, p1.x, a1.x); a1.y = fmaf(cn, p1.y, a1.y);
      a1.z = fmaf(cn, p1.z, a1.z); a1.w = fmaf(cn, p1.w, a1.w);
      a2.x = fmaf(cn, p2.x, a2.x); a2.y = fmaf(cn, p2.y, a2.y);
      a2.z = fmaf(cn, p2.z, a2.z); a2.w = fmaf(cn, p2.w, a2.w);
      a3.x = fmaf(cn, p3.x, a3.x); a3.y = fmaf(cn, p3.y, a3.y);
      a3.z = fmaf(cn, p3.z, a3.z); a3.w = fmaf(cn, p3.w, a3.w);
    }
    const float4* B4 = reinterpret_cast<const float4*>(b_proj) + eh * 4;
    const float4 bb0 = B4[0], bb1 = B4[1], bb2 = B4[2], bb3 = B4[3];
    float4* orow = reinterpret_cast<float4*>(out + ((size_t)(b * NQ + q)) * ND + eh * 16);
    orow[0] = make_float4(fmaf(a0.x, inv, bb0.x), fmaf(a0.y, inv, bb0.y),
                          fmaf(a0.z, inv, bb0.z), fmaf(a0.w, inv, bb0.w));
    orow[1] = make_float4(fmaf(a1.x, inv, bb1.x), fmaf(a1.y, inv, bb1.y),
                          fmaf(a1.z, inv, bb1.z), fmaf(a1.w, inv, bb1.w));
    orow[2] = make_float4(fmaf(a2.x, inv, bb2.x), fmaf(a2.y, inv, bb2.y),
                          fmaf(a2.z, inv, bb2.z), fmaf(a2.w, inv, bb2.w));
    orow[3] = make_float4(fmaf(a3.x, inv, bb3.x), fmaf(a3.y, inv, bb3.y),
                          fmaf(a3.z, inv, bb3.z), fmaf(a3.w, inv, bb3.w));
  }
}

extern "C" void kernel_launch(void* const* d_in, const int* in_sizes, int n_in,
                              void* d_out, int out_size, void* d_ws, size_t ws_size,
                              hipStream_t stream) {
  const float* obs_emb     = (const float*)d_in[0];
  const float* obs_times   = (const float*)d_in[1];
  const float* query_times = (const float*)d_in[2];
  const float* obs_mask    = (const float*)d_in[3];
  const float* log_sigma   = (const float*)d_in[4];
  const float* W_proj      = (const float*)d_in[5];
  const float* b_proj      = (const float*)d_in[6];
  float* out = (float*)d_out;

  float* Mpart = (float*)d_ws;                          // 8*16*12*128 f32 = 786 KB
  float* spart = Mpart + (size_t)NB * NCH * R * ND;     // 8*16*12

  moment_kernel<<<NB * NCH, 512, 0, stream>>>(obs_emb, obs_times, obs_mask,
                                              log_sigma, Mpart, spart);
  out_kernel<<<NB * (NQ / 64), 512, 0, stream>>>(query_times, W_proj, b_proj,
                                                 Mpart, spart, out);
}

// Round 10
// 23.809 us; speedup vs baseline: 5.1505x; 2.0294x over previous
//
#include <hip/hip_runtime.h>

#define NB 8
#define NO 2048
#define NQ 2048
#define ND 128
#define R  12        // Taylor terms for exp(x), x = tq*to/sigma^2 in [0,1] -> err ~ 6e-9
#define NCH 16       // o-chunks of 128 per batch

// ---------------- kernel 1: partial moment accumulation ----------------
// grid 128 = 16 ch x 8 b (b = blk&7, XCD-aligned with K2's consumers).
// Mpart[b][ch][n][d] = sum_{o in chunk} coef[o][n] * obs_emb[b][o][d]
// spart[b][ch][n]    = sum_{o in chunk} coef[o][n]
// coef[o][n] = mask_o * exp(-k*to^2) * (to/sigma^2)^n / n!
// Register-slim: per-o scalars staged in LDS, ev streamed (no hoisted arrays).
__global__ __launch_bounds__(512) void moment_kernel(
    const float* __restrict__ obs_emb, const float* __restrict__ obs_times,
    const float* __restrict__ obs_mask, const float* __restrict__ log_sigma,
    float* __restrict__ Mpart, float* __restrict__ spart)
{
  __shared__ float Lacc[4 * R * ND];   // 24 KB
  __shared__ float c0_s[128], u_s[128];
  __shared__ float Ls[4][R];
  const int tid   = threadIdx.x;
  const int d     = tid & 127;
  const int osub  = tid >> 7;          // 0..3, 32 o's each
  const int b     = blockIdx.x & 7;
  const int ch    = blockIdx.x >> 3;
  const int obase = ch * 128;

  const float ls     = log_sigma[0];
  const float inv_s2 = __expf(-2.0f * ls);   // 1/sigma^2
  const float kp     = 0.5f * inv_s2;

  // stage per-o weight scalars once per block
  if (tid < 128) {
    const float to = obs_times[b * NO + obase + tid];
    const float mk = obs_mask[b * NO + obase + tid];
    c0_s[tid] = mk * __expf(-kp * to * to);
    u_s[tid]  = to * inv_s2;
  }
  __syncthreads();

  const float inv_np1[R] = {1.f, 0.5f, 1.f/3.f, 0.25f, 0.2f, 1.f/6.f,
                            1.f/7.f, 0.125f, 1.f/9.f, 0.1f, 1.f/11.f, 1.f/12.f};
  float acc[R], sl[R];
  #pragma unroll
  for (int n = 0; n < R; ++n) { acc[n] = 0.f; sl[n] = 0.f; }

  const float* eb = obs_emb + ((size_t)(b * NO + obase + osub * 32)) * ND + d;
  #pragma unroll 4
  for (int i = 0; i < 32; ++i) {
    const float ev = eb[(size_t)i * ND];
    const int   o  = osub * 32 + i;
    float c = c0_s[o];
    const float u = u_s[o];
    #pragma unroll
    for (int n = 0; n < R; ++n) {
      acc[n] = fmaf(c, ev, acc[n]);
      sl[n] += c;
      c *= u * inv_np1[n];
    }
  }

  #pragma unroll
  for (int n = 0; n < R; ++n) Lacc[(osub * R + n) * ND + d] = acc[n];
  if (d == 0) {
    #pragma unroll
    for (int n = 0; n < R; ++n) Ls[osub][n] = sl[n];
  }
  __syncthreads();

  float* Mout = Mpart + ((size_t)(b * NCH + ch)) * (R * ND);
  #pragma unroll
  for (int k = 0; k < 3; ++k) {
    const int e = k * 512 + tid;       // flat n*ND+d
    Mout[e] = (Lacc[e] + Lacc[1536 + e]) + (Lacc[3072 + e] + Lacc[4608 + e]);
  }
  if (tid < R)
    spart[(b * NCH + ch) * R + tid] =
        (Ls[0][tid] + Ls[1][tid]) + (Ls[2][tid] + Ls[3][tid]);
}

// ---------------- kernel 2: reduce + fold W + emit ----------------
// grid 256 = 8 b x 32 q-tiles(64 q); 512 threads.
// A: M[n][d] = sum_ch Mpart (98 KB, local-XCD L2); s[n] likewise.
// B: P[n][e] = sum_d M[n][d] * W[e][d]   (LDS, layout [eh][n][16] stride 196)
// C: out[q][e] = (sum_n tq^n P[n][e]) / max(sum_n tq^n s[n], 1e-8) + b[e]
__global__ __launch_bounds__(512) void out_kernel(
    const float* __restrict__ query_times, const float* __restrict__ W_proj,
    const float* __restrict__ b_proj, const float* __restrict__ Mpart,
    const float* __restrict__ spart, float* __restrict__ out)
{
  __shared__ float Ml[R * ND];        // 6 KB
  __shared__ float Pl[8 * 196];       // 6.3 KB
  __shared__ float slb[R];
  const int tid = threadIdx.x;
  const int b   = blockIdx.x & 7;
  const int q0  = (blockIdx.x >> 3) * 64;

  // phase A: chunk reduction (fixed order -> deterministic)
  {
    const float* Mp = Mpart + (size_t)b * NCH * (R * ND);
    #pragma unroll
    for (int k = 0; k < 3; ++k) {
      const int e = k * 512 + tid;
      float v0 = 0.f, v1 = 0.f, v2 = 0.f, v3 = 0.f;
      #pragma unroll
      for (int chh = 0; chh < NCH; chh += 4) {
        v0 += Mp[(chh + 0) * (R * ND) + e];
        v1 += Mp[(chh + 1) * (R * ND) + e];
        v2 += Mp[(chh + 2) * (R * ND) + e];
        v3 += Mp[(chh + 3) * (R * ND) + e];
      }
      Ml[e] = (v0 + v1) + (v2 + v3);
    }
    if (tid < R) {
      const float* sp = spart + b * NCH * R;
      float v = 0.f;
      #pragma unroll
      for (int chh = 0; chh < NCH; ++chh) v += sp[chh * R + tid];
      slb[tid] = v;
    }
  }
  __syncthreads();

  // phase B: P = M @ W^T  (thread: e = tid>>2, 3 n's at nh=(tid&3)*3)
  {
    const int e  = tid >> 2;
    const int nh = (tid & 3) * 3;
    const float4* Wr = reinterpret_cast<const float4*>(W_proj) + e * 32;
    const float4* M4 = reinterpret_cast<const float4*>(Ml);
    float p0 = 0.f, p1 = 0.f, p2 = 0.f;
    #pragma unroll 8
    for (int d4 = 0; d4 < 32; ++d4) {
      const float4 w  = Wr[d4];
      const float4 m0 = M4[(nh + 0) * 32 + d4];
      const float4 m1 = M4[(nh + 1) * 32 + d4];
      const float4 m2 = M4[(nh + 2) * 32 + d4];
      p0 = fmaf(w.x, m0.x, fmaf(w.y, m0.y, fmaf(w.z, m0.z, fmaf(w.w, m0.w, p0))));
      p1 = fmaf(w.x, m1.x, fmaf(w.y, m1.y, fmaf(w.z, m1.z, fmaf(w.w, m1.w, p1))));
      p2 = fmaf(w.x, m2.x, fmaf(w.y, m2.y, fmaf(w.z, m2.z, fmaf(w.w, m2.w, p2))));
    }
    Pl[(e >> 4) * 196 + (nh + 0) * 16 + (e & 15)] = p0;
    Pl[(e >> 4) * 196 + (nh + 1) * 16 + (e & 15)] = p1;
    Pl[(e >> 4) * 196 + (nh + 2) * 16 + (e & 15)] = p2;
  }
  __syncthreads();

  // phase C: emit (thread: q = q0 + tid>>3, e-range [eh*16, +16))
  {
    const int q  = q0 + (tid >> 3);
    const int eh = tid & 7;
    const float tq = query_times[b * NQ + q];

    float c[R];
    c[0] = 1.f;
    #pragma unroll
    for (int n = 1; n < R; ++n) c[n] = c[n - 1] * tq;
    float wsum = 0.f;
    #pragma unroll
    for (int n = 0; n < R; ++n) wsum = fmaf(c[n], slb[n], wsum);
    const float inv = 1.0f / fmaxf(wsum, 1e-8f);

    const float* Pe = Pl + eh * 196;
    float4 a0 = {0,0,0,0}, a1 = {0,0,0,0}, a2 = {0,0,0,0}, a3 = {0,0,0,0};
    #pragma unroll
    for (int n = 0; n < R; ++n) {
      const float cn = c[n];
      const float4 p0 = *reinterpret_cast<const float4*>(Pe + n * 16 + 0);
      const float4 p1 = *reinterpret_cast<const float4*>(Pe + n * 16 + 4);
      const float4 p2 = *reinterpret_cast<const float4*>(Pe + n * 16 + 8);
      const float4 p3 = *reinterpret_cast<const float4*>(Pe + n * 16 + 12);
      a0.x = fmaf(cn, p0.x, a0.x); a0.y = fmaf(cn, p0.y, a0.y);
      a0.z = fmaf(cn, p0.z, a0.z); a0.w = fmaf(cn, p0.w, a0.w);
      a1.x = fmaf(cn, p1.x, a1.x); a1.y = fmaf(cn, p1.y, a1.y);
      a1.z = fmaf(cn, p1.z, a1.z); a1.w = fmaf(cn, p1.w, a1.w);
      a2.x = fmaf(cn, p2.x, a2.x); a2.y = fmaf(cn, p2.y, a2.y);
      a2.z = fmaf(cn, p2.z, a2.z); a2.w = fmaf(cn, p2.w, a2.w);
      a3.x = fmaf(cn, p3.x, a3.x); a3.y = fmaf(cn, p3.y, a3.y);
      a3.z = fmaf(cn, p3.z, a3.z); a3.w = fmaf(cn, p3.w, a3.w);
    }
    const float4* B4 = reinterpret_cast<const float4*>(b_proj) + eh * 4;
    const float4 bb0 = B4[0], bb1 = B4[1], bb2 = B4[2], bb3 = B4[3];
    float4* orow = reinterpret_cast<float4*>(out + ((size_t)(b * NQ + q)) * ND + eh * 16);
    orow[0] = make_float4(fmaf(a0.x, inv, bb0.x), fmaf(a0.y, inv, bb0.y),
                          fmaf(a0.z, inv, bb0.z), fmaf(a0.w, inv, bb0.w));
    orow[1] = make_float4(fmaf(a1.x, inv, bb1.x), fmaf(a1.y, inv, bb1.y),
                          fmaf(a1.z, inv, bb1.z), fmaf(a1.w, inv, bb1.w));
    orow[2] = make_float4(fmaf(a2.x, inv, bb2.x), fmaf(a2.y, inv, bb2.y),
                          fmaf(a2.z, inv, bb2.z), fmaf(a2.w, inv, bb2.w));
    orow[3] = make_float4(fmaf(a3.x, inv, bb3.x), fmaf(a3.y, inv, bb3.y),
                          fmaf(a3.z, inv, bb3.z), fmaf(a3.w, inv, bb3.w));
  }
}

extern "C" void kernel_launch(void* const* d_in, const int* in_sizes, int n_in,
                              void* d_out, int out_size, void* d_ws, size_t ws_size,
                              hipStream_t stream) {
  const float* obs_emb     = (const float*)d_in[0];
  const float* obs_times   = (const float*)d_in[1];
  const float* query_times = (const float*)d_in[2];
  const float* obs_mask    = (const float*)d_in[3];
  const float* log_sigma   = (const float*)d_in[4];
  const float* W_proj      = (const float*)d_in[5];
  const float* b_proj      = (const float*)d_in[6];
  float* out = (float*)d_out;

  float* Mpart = (float*)d_ws;                          // 8*16*12*128 f32 = 786 KB
  float* spart = Mpart + (size_t)NB * NCH * R * ND;     // 8*16*12

  moment_kernel<<<NB * NCH, 512, 0, stream>>>(obs_emb, obs_times, obs_mask,
                                              log_sigma, Mpart, spart);
  out_kernel<<<NB * (NQ / 64), 512, 0, stream>>>(query_times, W_proj, b_proj,
                                                 Mpart, spart, out);
}

// Round 11
// 22.751 us; speedup vs baseline: 5.3899x; 1.0465x over previous
//
#include <hip/hip_runtime.h>

#define NB 8
#define NO 2048
#define NQ 2048
#define ND 128
#define R  12        // Taylor terms for exp(x), x = tq*to/sigma^2 in [0,1] -> err ~ 6e-9
#define NCH 32       // o-chunks of 64 per batch

// ---------------- kernel 1: partial moment accumulation ----------------
// grid 256 = 32 ch x 8 b (b = blk&7, XCD-aligned with K2's consumers); block 512.
// Mpart[b][ch][n][d] = sum_{o in chunk} coef[o][n] * obs_emb[b][o][d]
// spart[b][ch][n]    = sum_{o in chunk} coef[o][n]
// coef[o][n] = mask_o * exp(-k*to^2) * (to/sigma^2)^n / n!
// coef table precomputed in LDS -> inner loop = 1 gld + 3 broadcast ds_reads + 12 fma.
__global__ __launch_bounds__(512) void moment_kernel(
    const float* __restrict__ obs_emb, const float* __restrict__ obs_times,
    const float* __restrict__ obs_mask, const float* __restrict__ log_sigma,
    float* __restrict__ Mpart, float* __restrict__ spart)
{
  __shared__ float Lacc[4 * R * ND];              // 24 KB
  __shared__ __align__(16) float coef_s[64 * R];  // 3 KB, row-major [o][n]
  const int tid   = threadIdx.x;
  const int d     = tid & 127;
  const int osub  = tid >> 7;          // 0..3, 16 o's each
  const int b     = blockIdx.x & 7;
  const int ch    = blockIdx.x >> 3;
  const int obase = ch * 64;

  const float ls     = log_sigma[0];
  const float inv_s2 = __expf(-2.0f * ls);   // 1/sigma^2
  const float kp     = 0.5f * inv_s2;

  // stage full coefficient table once per block (chain done once, here)
  if (tid < 64) {
    const float to = obs_times[b * NO + obase + tid];
    const float mk = obs_mask[b * NO + obase + tid];
    const float u  = to * inv_s2;
    const float inv_np1[R] = {1.f, 0.5f, 1.f/3.f, 0.25f, 0.2f, 1.f/6.f,
                              1.f/7.f, 0.125f, 1.f/9.f, 0.1f, 1.f/11.f, 1.f/12.f};
    float c = mk * __expf(-kp * to * to);
    #pragma unroll
    for (int n = 0; n < R; ++n) {
      coef_s[tid * R + n] = c;
      c *= u * inv_np1[n];
    }
  }
  __syncthreads();

  float acc[R];
  #pragma unroll
  for (int n = 0; n < R; ++n) acc[n] = 0.f;

  const float* eb = obs_emb + ((size_t)(b * NO + obase + osub * 16)) * ND + d;
  #pragma unroll 4
  for (int i = 0; i < 16; ++i) {
    const float ev = eb[(size_t)i * ND];
    const float4* cf = reinterpret_cast<const float4*>(coef_s + (osub * 16 + i) * R);
    const float4 c0 = cf[0], c1 = cf[1], c2 = cf[2];   // broadcast reads (free)
    acc[0]  = fmaf(c0.x, ev, acc[0]);   acc[1]  = fmaf(c0.y, ev, acc[1]);
    acc[2]  = fmaf(c0.z, ev, acc[2]);   acc[3]  = fmaf(c0.w, ev, acc[3]);
    acc[4]  = fmaf(c1.x, ev, acc[4]);   acc[5]  = fmaf(c1.y, ev, acc[5]);
    acc[6]  = fmaf(c1.z, ev, acc[6]);   acc[7]  = fmaf(c1.w, ev, acc[7]);
    acc[8]  = fmaf(c2.x, ev, acc[8]);   acc[9]  = fmaf(c2.y, ev, acc[9]);
    acc[10] = fmaf(c2.z, ev, acc[10]);  acc[11] = fmaf(c2.w, ev, acc[11]);
  }

  #pragma unroll
  for (int n = 0; n < R; ++n) Lacc[(osub * R + n) * ND + d] = acc[n];
  __syncthreads();

  float* Mout = Mpart + ((size_t)(b * NCH + ch)) * (R * ND);
  #pragma unroll
  for (int k = 0; k < 3; ++k) {
    const int e = k * 512 + tid;       // flat n*ND+d
    Mout[e] = (Lacc[e] + Lacc[1536 + e]) + (Lacc[3072 + e] + Lacc[4608 + e]);
  }
  if (tid < R) {
    float v = 0.f;
    #pragma unroll
    for (int o = 0; o < 64; ++o) v += coef_s[o * R + tid];
    spart[(b * NCH + ch) * R + tid] = v;
  }
}

// ---------------- kernel 2: reduce + fold W + emit ----------------
// grid 256 = 8 b x 32 q-tiles(64 q); 512 threads.
// A: M[n][d] = sum_ch Mpart (196 KB, XCD-local L2); s[n] likewise.
// B: P[n][e] = sum_d M[n][d] * W[e][d]   (LDS, layout [eh][n][16] stride 196)
// C: out[q][e] = (sum_n tq^n P[n][e]) / max(sum_n tq^n s[n], 1e-8) + b[e]
__global__ __launch_bounds__(512) void out_kernel(
    const float* __restrict__ query_times, const float* __restrict__ W_proj,
    const float* __restrict__ b_proj, const float* __restrict__ Mpart,
    const float* __restrict__ spart, float* __restrict__ out)
{
  __shared__ float Ml[R * ND];        // 6 KB
  __shared__ float Pl[8 * 196];       // 6.3 KB
  __shared__ float slb[R];
  const int tid = threadIdx.x;
  const int b   = blockIdx.x & 7;
  const int q0  = (blockIdx.x >> 3) * 64;

  // phase A: chunk reduction (fixed order -> deterministic)
  {
    const float* Mp = Mpart + (size_t)b * NCH * (R * ND);
    #pragma unroll
    for (int k = 0; k < 3; ++k) {
      const int e = k * 512 + tid;
      float v0 = 0.f, v1 = 0.f, v2 = 0.f, v3 = 0.f;
      #pragma unroll
      for (int chh = 0; chh < NCH; chh += 4) {
        v0 += Mp[(chh + 0) * (R * ND) + e];
        v1 += Mp[(chh + 1) * (R * ND) + e];
        v2 += Mp[(chh + 2) * (R * ND) + e];
        v3 += Mp[(chh + 3) * (R * ND) + e];
      }
      Ml[e] = (v0 + v1) + (v2 + v3);
    }
    if (tid < R) {
      const float* sp = spart + b * NCH * R;
      float v = 0.f;
      #pragma unroll
      for (int chh = 0; chh < NCH; ++chh) v += sp[chh * R + tid];
      slb[tid] = v;
    }
  }
  __syncthreads();

  // phase B: P = M @ W^T  (thread: e = tid>>2, 3 n's at nh=(tid&3)*3)
  {
    const int e  = tid >> 2;
    const int nh = (tid & 3) * 3;
    const float4* Wr = reinterpret_cast<const float4*>(W_proj) + e * 32;
    const float4* M4 = reinterpret_cast<const float4*>(Ml);
    float p0 = 0.f, p1 = 0.f, p2 = 0.f;
    #pragma unroll 8
    for (int d4 = 0; d4 < 32; ++d4) {
      const float4 w  = Wr[d4];
      const float4 m0 = M4[(nh + 0) * 32 + d4];
      const float4 m1 = M4[(nh + 1) * 32 + d4];
      const float4 m2 = M4[(nh + 2) * 32 + d4];
      p0 = fmaf(w.x, m0.x, fmaf(w.y, m0.y, fmaf(w.z, m0.z, fmaf(w.w, m0.w, p0))));
      p1 = fmaf(w.x, m1.x, fmaf(w.y, m1.y, fmaf(w.z, m1.z, fmaf(w.w, m1.w, p1))));
      p2 = fmaf(w.x, m2.x, fmaf(w.y, m2.y, fmaf(w.z, m2.z, fmaf(w.w, m2.w, p2))));
    }
    Pl[(e >> 4) * 196 + (nh + 0) * 16 + (e & 15)] = p0;
    Pl[(e >> 4) * 196 + (nh + 1) * 16 + (e & 15)] = p1;
    Pl[(e >> 4) * 196 + (nh + 2) * 16 + (e & 15)] = p2;
  }
  __syncthreads();

  // phase C: emit (thread: q = q0 + tid>>3, e-range [eh*16, +16))
  {
    const int q  = q0 + (tid >> 3);
    const int eh = tid & 7;
    const float tq = query_times[b * NQ + q];

    float c[R];
    c[0] = 1.f;
    #pragma unroll
    for (int n = 1; n < R; ++n) c[n] = c[n - 1] * tq;
    float wsum = 0.f;
    #pragma unroll
    for (int n = 0; n < R; ++n) wsum = fmaf(c[n], slb[n], wsum);
    const float inv = 1.0f / fmaxf(wsum, 1e-8f);

    const float* Pe = Pl + eh * 196;
    float4 a0 = {0,0,0,0}, a1 = {0,0,0,0}, a2 = {0,0,0,0}, a3 = {0,0,0,0};
    #pragma unroll
    for (int n = 0; n < R; ++n) {
      const float cn = c[n];
      const float4 p0 = *reinterpret_cast<const float4*>(Pe + n * 16 + 0);
      const float4 p1 = *reinterpret_cast<const float4*>(Pe + n * 16 + 4);
      const float4 p2 = *reinterpret_cast<const float4*>(Pe + n * 16 + 8);
      const float4 p3 = *reinterpret_cast<const float4*>(Pe + n * 16 + 12);
      a0.x = fmaf(cn, p0.x, a0.x); a0.y = fmaf(cn, p0.y, a0.y);
      a0.z = fmaf(cn, p0.z, a0.z); a0.w = fmaf(cn, p0.w, a0.w);
      a1.x = fmaf(cn, p1.x, a1.x); a1.y = fmaf(cn, p1.y, a1.y);
      a1.z = fmaf(cn, p1.z, a1.z); a1.w = fmaf(cn, p1.w, a1.w);
      a2.x = fmaf(cn, p2.x, a2.x); a2.y = fmaf(cn, p2.y, a2.y);
      a2.z = fmaf(cn, p2.z, a2.z); a2.w = fmaf(cn, p2.w, a2.w);
      a3.x = fmaf(cn, p3.x, a3.x); a3.y = fmaf(cn, p3.y, a3.y);
      a3.z = fmaf(cn, p3.z, a3.z); a3.w = fmaf(cn, p3.w, a3.w);
    }
    const float4* B4 = reinterpret_cast<const float4*>(b_proj) + eh * 4;
    const float4 bb0 = B4[0], bb1 = B4[1], bb2 = B4[2], bb3 = B4[3];
    float4* orow = reinterpret_cast<float4*>(out + ((size_t)(b * NQ + q)) * ND + eh * 16);
    orow[0] = make_float4(fmaf(a0.x, inv, bb0.x), fmaf(a0.y, inv, bb0.y),
                          fmaf(a0.z, inv, bb0.z), fmaf(a0.w, inv, bb0.w));
    orow[1] = make_float4(fmaf(a1.x, inv, bb1.x), fmaf(a1.y, inv, bb1.y),
                          fmaf(a1.z, inv, bb1.z), fmaf(a1.w, inv, bb1.w));
    orow[2] = make_float4(fmaf(a2.x, inv, bb2.x), fmaf(a2.y, inv, bb2.y),
                          fmaf(a2.z, inv, bb2.z), fmaf(a2.w, inv, bb2.w));
    orow[3] = make_float4(fmaf(a3.x, inv, bb3.x), fmaf(a3.y, inv, bb3.y),
                          fmaf(a3.z, inv, bb3.z), fmaf(a3.w, inv, bb3.w));
  }
}

extern "C" void kernel_launch(void* const* d_in, const int* in_sizes, int n_in,
                              void* d_out, int out_size, void* d_ws, size_t ws_size,
                              hipStream_t stream) {
  const float* obs_emb     = (const float*)d_in[0];
  const float* obs_times   = (const float*)d_in[1];
  const float* query_times = (const float*)d_in[2];
  const float* obs_mask    = (const float*)d_in[3];
  const float* log_sigma   = (const float*)d_in[4];
  const float* W_proj      = (const float*)d_in[5];
  const float* b_proj      = (const float*)d_in[6];
  float* out = (float*)d_out;

  float* Mpart = (float*)d_ws;                          // 8*32*12*128 f32 = 1.57 MB
  float* spart = Mpart + (size_t)NB * NCH * R * ND;     // 8*32*12

  moment_kernel<<<NB * NCH, 512, 0, stream>>>(obs_emb, obs_times, obs_mask,
                                              log_sigma, Mpart, spart);
  out_kernel<<<NB * (NQ / 64), 512, 0, stream>>>(query_times, W_proj, b_proj,
                                                 Mpart, spart, out);
}